// Round 2
// baseline (217.070 us; speedup 1.0000x reference)
//
#include <hip/hip_runtime.h>

typedef short bf16x8 __attribute__((ext_vector_type(8)));
typedef float f32x4 __attribute__((ext_vector_type(4)));

#define NEG_INF (-__builtin_inff())

static __device__ __forceinline__ unsigned short f2bf(float f) {
  union { float f; unsigned u; } v; v.f = f;
  return (unsigned short)((v.u + 0x7fffu + ((v.u >> 16) & 1u)) >> 16);
}

static __device__ __forceinline__ f32x4 mfma16(bf16x8 a, bf16x8 b, f32x4 c) {
  return __builtin_amdgcn_mfma_f32_16x16x32_bf16(a, b, c, 0, 0, 0);
}

// ---------------- kernel 0: W -> W^T bf16 [192][384] (rows: Q 0-63, K 64-127, V 128-191)
__global__ __launch_bounds__(256) void prep_w(const float* __restrict__ wq,
                                              const float* __restrict__ wk,
                                              const float* __restrict__ wv,
                                              unsigned short* __restrict__ wt) {
  int i = blockIdx.x * 256 + threadIdx.x;
  if (i >= 384 * 64) return;
  int c = i >> 6, d = i & 63;
  wt[(long)d * 384 + c] = f2bf(wq[i]);
  wt[(long)(64 + d) * 384 + c] = f2bf(wk[i]);
  wt[(long)(128 + d) * 384 + c] = f2bf(wv[i]);
}

// ---------------- kernel 1: QKV projection ----------------
// 512 blocks x 256 threads; 4 independent waves, 16 tokens each. No barriers.
// Outputs: q,k [tok][64] bf16; v^T [b][64][2048] bf16.
__global__ __launch_bounds__(256, 2) void proj_kernel(
    const float* __restrict__ x, const unsigned short* __restrict__ wt,
    unsigned short* __restrict__ qo, unsigned short* __restrict__ ko,
    unsigned short* __restrict__ vto) {
  __shared__ unsigned short tq[4][16][72];
  __shared__ unsigned short tk[4][16][72];
  __shared__ unsigned short tv[4][64][24];
  const int tid = threadIdx.x;
  const int wave = tid >> 6, lane = tid & 63;
  const int lo = lane & 15, quad = lane >> 4;
  const long tok0 = (long)blockIdx.x * 64 + wave * 16;

  f32x4 acc[12];
#pragma unroll
  for (int nt = 0; nt < 12; ++nt) acc[nt] = (f32x4){0.f, 0.f, 0.f, 0.f};

#pragma unroll
  for (int kk = 0; kk < 12; ++kk) {
    const float* xr = x + (tok0 + lo) * 384 + kk * 32 + quad * 8;
    float4 x0 = *(const float4*)xr;
    float4 x1 = *(const float4*)(xr + 4);
    bf16x8 ax;
    ax[0] = (short)f2bf(x0.x); ax[1] = (short)f2bf(x0.y);
    ax[2] = (short)f2bf(x0.z); ax[3] = (short)f2bf(x0.w);
    ax[4] = (short)f2bf(x1.x); ax[5] = (short)f2bf(x1.y);
    ax[6] = (short)f2bf(x1.z); ax[7] = (short)f2bf(x1.w);
    const unsigned short* wb = wt + kk * 32 + quad * 8;
#pragma unroll
    for (int nt = 0; nt < 12; ++nt) {
      bf16x8 bw = *(const bf16x8*)(wb + (long)(nt * 16 + lo) * 384);
      acc[nt] = mfma16(ax, bw, acc[nt]);
    }
  }
  // epilogue: transpose through wave-private LDS, then coalesced 16B stores.
#pragma unroll
  for (int nt = 0; nt < 4; ++nt)
#pragma unroll
    for (int r = 0; r < 4; ++r) {
      tq[wave][quad * 4 + r][nt * 16 + lo] = f2bf(acc[nt][r]);
      tk[wave][quad * 4 + r][nt * 16 + lo] = f2bf(acc[4 + nt][r]);
    }
#pragma unroll
  for (int nt = 0; nt < 4; ++nt) {
    ushort4 pk;
    pk.x = f2bf(acc[8 + nt][0]); pk.y = f2bf(acc[8 + nt][1]);
    pk.z = f2bf(acc[8 + nt][2]); pk.w = f2bf(acc[8 + nt][3]);
    *(ushort4*)&tv[wave][nt * 16 + lo][quad * 4] = pk;  // tv[d][tok]
  }
  asm volatile("s_waitcnt lgkmcnt(0)" ::: "memory");
  const long bb = blockIdx.x >> 5;                       // batch
  const int t0g = (blockIdx.x & 31) * 64 + wave * 16;    // token offset in batch
#pragma unroll
  for (int it = 0; it < 2; ++it) {
    bf16x8 vq = *(const bf16x8*)&tq[wave][lane >> 2][it * 32 + (lane & 3) * 8];
    bf16x8 vk = *(const bf16x8*)&tk[wave][lane >> 2][it * 32 + (lane & 3) * 8];
    *(bf16x8*)(qo + (tok0 + (lane >> 2)) * 64 + it * 32 + (lane & 3) * 8) = vq;
    *(bf16x8*)(ko + (tok0 + (lane >> 2)) * 64 + it * 32 + (lane & 3) * 8) = vk;
    bf16x8 vv = *(const bf16x8*)&tv[wave][lane][it * 8];
    *(bf16x8*)(vto + (bb * 64 + lane) * 2048 + t0g + it * 8) = vv;
  }
}

// ---------------- kernel 2: causal flash attention (S^T formulation) ----------------
// 512 blocks x 256 threads. Block (i,b): 4 independent waves, wave w owns q-tile
// j = 4i+w (16 rows); each wave does exactly i+1 key-tile iterations (balanced).
// Blocks issued biggest-first. No __syncthreads anywhere.
__global__ __launch_bounds__(256, 2) void attn_kernel(
    const unsigned short* __restrict__ qg, const unsigned short* __restrict__ kg,
    const unsigned short* __restrict__ vg, float* __restrict__ out) {
  __shared__ unsigned short ps[4][16][72];  // wave-private P^T tile [qrow][key]

  const int tid = threadIdx.x;
  const int wave = tid >> 6, lane = tid & 63;
  const int lo = lane & 15, quad = lane >> 4;
  const int b = blockIdx.x & 15;           // batch -> stable XCD residue (L2 locality)
  const int i = 31 - (blockIdx.x >> 4);    // biggest blocks first
  const int j = i * 4 + wave;              // q-tile 0..127
  const int niter = i + 1;
  const int qrow0 = j * 16;
  const float Cs = 0.18033688011112042f;   // 0.125 * log2(e)

  const unsigned short* qb = qg + (long)b * 2048 * 64;
  const unsigned short* kb = kg + (long)b * 2048 * 64;
  const unsigned short* vb = vg + (long)b * 64 * 2048;  // [64][2048]
  float* ob = out + (long)b * 2048 * 64;

  // Q as B-operand: B[k=quad*8+jj][n=lo] = Q[qrow0+lo][c]
  const unsigned short* qr = qb + (long)(qrow0 + lo) * 64 + quad * 8;
  const bf16x8 bq0 = *(const bf16x8*)qr;
  const bf16x8 bq1 = *(const bf16x8*)(qr + 32);

  f32x4 oacc[4];
#pragma unroll
  for (int dt = 0; dt < 4; ++dt) oacc[dt] = (f32x4){0.f, 0.f, 0.f, 0.f};
  float m = NEG_INF, l = 0.f;

  for (int kt = 0; kt < niter; ++kt) {
    const int key0 = kt * 64;
    const bool diag = (kt == niter - 1);
    const int tmax = diag ? (j & 3) : 3;

    // V^T A-fragments for this key tile — issue early, consumed after softmax.
    bf16x8 av[2][4];
#pragma unroll
    for (int kk2 = 0; kk2 < 2; ++kk2)
#pragma unroll
      for (int dt = 0; dt < 4; ++dt)
        av[kk2][dt] = *(const bf16x8*)(vb + (long)(dt * 16 + lo) * 2048 + key0 +
                                       kk2 * 32 + quad * 8);

    // S^T = K Q^T : A = K rows (m=key), B = Q rows (n=qrow)
    f32x4 s[4];
#pragma unroll
    for (int t = 0; t < 4; ++t) {
      if (t <= tmax) {
        const unsigned short* kr = kb + (long)(key0 + t * 16 + lo) * 64 + quad * 8;
        bf16x8 ak0 = *(const bf16x8*)kr;
        bf16x8 ak1 = *(const bf16x8*)(kr + 32);
        s[t] = (f32x4){0.f, 0.f, 0.f, 0.f};
        s[t] = mfma16(ak0, bq0, s[t]);
        s[t] = mfma16(ak1, bq1, s[t]);
      } else {
        s[t] = (f32x4){NEG_INF, NEG_INF, NEG_INF, NEG_INF};
      }
    }
    if (diag) {
      const int qrl = qrow0 + lo;
#pragma unroll
      for (int t = 0; t < 4; ++t)
#pragma unroll
        for (int r = 0; r < 4; ++r)
          if (key0 + t * 16 + quad * 4 + r > qrl) s[t][r] = NEG_INF;
    }
    // online softmax: m/l scalar per lane (qrow = lo); l is per-lane partial.
    float mx = s[0][0];
#pragma unroll
    for (int t = 0; t < 4; ++t)
#pragma unroll
      for (int r = 0; r < 4; ++r) mx = fmaxf(mx, s[t][r]);
    mx = fmaxf(mx, __shfl_xor(mx, 16, 64));
    mx = fmaxf(mx, __shfl_xor(mx, 32, 64));
    const float mnew = fmaxf(m, mx);
    const float alpha = exp2f((m - mnew) * Cs);
    m = mnew;
    float psum = 0.f;
#pragma unroll
    for (int t = 0; t < 4; ++t)
#pragma unroll
      for (int r = 0; r < 4; ++r) {
        float p = exp2f((s[t][r] - mnew) * Cs);
        s[t][r] = p;
        psum += p;
      }
    l = l * alpha + psum;
#pragma unroll
    for (int dt = 0; dt < 4; ++dt)
#pragma unroll
      for (int r = 0; r < 4; ++r) oacc[dt][r] *= alpha;

    // P^T (C-layout) -> ps[qrow][key] : per lane 4 consecutive keys -> b64 writes
#pragma unroll
    for (int t = 0; t < 4; ++t) {
      ushort4 pk;
      pk.x = f2bf(s[t][0]); pk.y = f2bf(s[t][1]);
      pk.z = f2bf(s[t][2]); pk.w = f2bf(s[t][3]);
      *(ushort4*)&ps[wave][lo][t * 16 + quad * 4] = pk;
    }
    asm volatile("s_waitcnt lgkmcnt(0)" ::: "memory");  // wave-private, no barrier
    // O^T += V^T P^T : A = V^T (m=d), B = P^T (n=qrow)
#pragma unroll
    for (int kk2 = 0; kk2 < 2; ++kk2) {
      bf16x8 bp = *(const bf16x8*)&ps[wave][lo][kk2 * 32 + quad * 8];
#pragma unroll
      for (int dt = 0; dt < 4; ++dt) oacc[dt] = mfma16(av[kk2][dt], bp, oacc[dt]);
    }
  }
  // epilogue: finish l across the 4 quads, normalize, coalesced float4 stores.
  l += __shfl_xor(l, 16, 64);
  l += __shfl_xor(l, 32, 64);
  const float inv = 1.0f / l;
  float* orow = ob + (long)(qrow0 + lo) * 64;
#pragma unroll
  for (int dt = 0; dt < 4; ++dt) {
    float4 st;
    st.x = oacc[dt][0] * inv; st.y = oacc[dt][1] * inv;
    st.z = oacc[dt][2] * inv; st.w = oacc[dt][3] * inv;
    *(float4*)(orow + dt * 16 + quad * 4) = st;
  }
}

// ---------------- launcher ----------------
extern "C" void kernel_launch(void* const* d_in, const int* in_sizes, int n_in,
                              void* d_out, int out_size, void* d_ws, size_t ws_size,
                              hipStream_t stream) {
  const float* x = (const float*)d_in[0];
  const float* wq = (const float*)d_in[1];
  const float* wk = (const float*)d_in[2];
  const float* wv = (const float*)d_in[3];
  float* out = (float*)d_out;

  char* ws = (char*)d_ws;
  unsigned short* wt = (unsigned short*)ws;  // 192*384*2 = 147456 B
  const size_t qkv_elems = (size_t)16 * 2048 * 64;
  unsigned short* qws = (unsigned short*)(ws + 147456);
  unsigned short* kws = qws + qkv_elems;
  unsigned short* vws = kws + qkv_elems;

  prep_w<<<96, 256, 0, stream>>>(wq, wk, wv, wt);
  proj_kernel<<<512, 256, 0, stream>>>(x, wt, qws, kws, vws);
  attn_kernel<<<512, 256, 0, stream>>>(qws, kws, vws, out);
}

// Round 3
// 204.562 us; speedup vs baseline: 1.0611x; 1.0611x over previous
//
#include <hip/hip_runtime.h>

typedef short bf16x8 __attribute__((ext_vector_type(8)));
typedef float f32x4 __attribute__((ext_vector_type(4)));

#define NEG_INF (-__builtin_inff())

static __device__ __forceinline__ unsigned short f2bf(float f) {
  union { float f; unsigned u; } v; v.f = f;
  return (unsigned short)((v.u + 0x7fffu + ((v.u >> 16) & 1u)) >> 16);
}

static __device__ __forceinline__ f32x4 mfma16(bf16x8 a, bf16x8 b, f32x4 c) {
  return __builtin_amdgcn_mfma_f32_16x16x32_bf16(a, b, c, 0, 0, 0);
}

// ---------------- kernel 0: W -> W^T bf16 [192][384] (rows: Q 0-63, K 64-127, V 128-191)
__global__ __launch_bounds__(256) void prep_w(const float* __restrict__ wq,
                                              const float* __restrict__ wk,
                                              const float* __restrict__ wv,
                                              unsigned short* __restrict__ wt) {
  int i = blockIdx.x * 256 + threadIdx.x;
  if (i >= 384 * 64) return;
  int c = i >> 6, d = i & 63;
  wt[(long)d * 384 + c] = f2bf(wq[i]);
  wt[(long)(64 + d) * 384 + c] = f2bf(wk[i]);
  wt[(long)(128 + d) * 384 + c] = f2bf(wv[i]);
}

// ---------------- kernel 1: QKV projection ----------------
// 1024 blocks x 4 waves. Wave-task = (16-token m-tile, half of the 12 output
// n-tiles). 4 blocks/CU -> 4 waves/SIMD. No LDS, no barriers.
// V accumulated with swapped MFMA operands -> C[d][tok] stored directly as v^T.
__global__ __launch_bounds__(256, 4) void proj_kernel(
    const float* __restrict__ x, const unsigned short* __restrict__ wt,
    unsigned short* __restrict__ qo, unsigned short* __restrict__ ko,
    unsigned short* __restrict__ vto) {
  const int tid = threadIdx.x;
  const int wave = tid >> 6, lane = tid & 63;
  const int lo = lane & 15, quad = lane >> 4;
  const int m = blockIdx.x * 2 + (wave & 1);  // m-tile 0..2047
  const int nh = wave >> 1;                   // n-half: nt = nh*6 .. nh*6+5
  const long tok0 = (long)m * 16;

  f32x4 acc[6];
#pragma unroll
  for (int n = 0; n < 6; ++n) acc[n] = (f32x4){0.f, 0.f, 0.f, 0.f};

  const float* xr = x + (tok0 + lo) * 384 + quad * 8;
#pragma unroll
  for (int kk = 0; kk < 12; ++kk) {
    float4 x0 = *(const float4*)(xr + kk * 32);
    float4 x1 = *(const float4*)(xr + kk * 32 + 4);
    bf16x8 ax;
    ax[0] = (short)f2bf(x0.x); ax[1] = (short)f2bf(x0.y);
    ax[2] = (short)f2bf(x0.z); ax[3] = (short)f2bf(x0.w);
    ax[4] = (short)f2bf(x1.x); ax[5] = (short)f2bf(x1.y);
    ax[6] = (short)f2bf(x1.z); ax[7] = (short)f2bf(x1.w);
#pragma unroll
    for (int n = 0; n < 6; ++n) {
      const int nt = nh * 6 + n;
      bf16x8 bw = *(const bf16x8*)(wt + (long)(nt * 16 + lo) * 384 + kk * 32 + quad * 8);
      if (nt < 8)
        acc[n] = mfma16(ax, bw, acc[n]);  // C[tok][d]
      else
        acc[n] = mfma16(bw, ax, acc[n]);  // C[d][tok]  (V transposed)
    }
  }
  // stores
  const long bb = m >> 7;            // batch
  const int tokg = (int)(tok0 & 2047);
#pragma unroll
  for (int n = 0; n < 6; ++n) {
    const int nt = nh * 6 + n;
    if (nt < 4) {
#pragma unroll
      for (int r = 0; r < 4; ++r)
        qo[(tok0 + quad * 4 + r) * 64 + nt * 16 + lo] = f2bf(acc[n][r]);
    } else if (nt < 8) {
#pragma unroll
      for (int r = 0; r < 4; ++r)
        ko[(tok0 + quad * 4 + r) * 64 + (nt - 4) * 16 + lo] = f2bf(acc[n][r]);
    } else {
#pragma unroll
      for (int r = 0; r < 4; ++r)
        vto[(bb * 64 + (nt - 8) * 16 + quad * 4 + r) * 2048 + tokg + lo] = f2bf(acc[n][r]);
    }
  }
}

// ---------------- kernel 2: causal flash attention, 2-way split-K ----------------
// 1024 blocks x 4 waves. Block (a,b): q-tiles {2a, 2a+1}; wave w = (jj=w&1, h=w>>1)
// computes key-tiles [0,h1) or [h1,nb) of q-tile 2a+jj. No running max (logits are
// hard-bounded, exp2 cannot overflow); merge = pure add via LDS + one barrier.
__global__ __launch_bounds__(256, 4) void attn_kernel(
    const unsigned short* __restrict__ qg, const unsigned short* __restrict__ kg,
    const unsigned short* __restrict__ vg, float* __restrict__ out) {
  __shared__ unsigned short ps[4][16][70];   // wave-private P^T tile [qrow][key]
  __shared__ float olds[2][16][65];          // h=1 partial O [qrow][d]
  __shared__ float llds[2][2][4][16];        // [jj][h][quad][qrow] partial l

  const int tid = threadIdx.x;
  const int wave = tid >> 6, lane = tid & 63;
  const int lo = lane & 15, quad = lane >> 4;
  const int b = blockIdx.x & 15;
  const int a = 63 - (blockIdx.x >> 4);      // biggest blocks first
  const int jj = wave & 1, h = wave >> 1;
  const int j = 2 * a + jj;                  // q-tile 0..127
  const int nb = (j >> 2) + 1;               // total key tiles for this q-tile
  const int h1 = (nb + 1) >> 1;
  const int kt0 = h ? h1 : 0;
  const int kt1 = h ? nb : h1;
  const int qrow0 = j * 16;
  const float Cs = 0.18033688011112042f;     // 0.125 * log2(e)

  const unsigned short* qb = qg + (long)b * 2048 * 64;
  const unsigned short* kb = kg + (long)b * 2048 * 64;
  const unsigned short* vb = vg + (long)b * 64 * 2048;  // [64][2048]
  float* ob = out + (long)b * 2048 * 64;

  // Q as B-operand: B[k=quad*8+t][n=lo]
  const unsigned short* qr = qb + (long)(qrow0 + lo) * 64 + quad * 8;
  const bf16x8 bq0 = *(const bf16x8*)qr;
  const bf16x8 bq1 = *(const bf16x8*)(qr + 32);

  f32x4 oacc[4];
#pragma unroll
  for (int dt = 0; dt < 4; ++dt) oacc[dt] = (f32x4){0.f, 0.f, 0.f, 0.f};
  float l = 0.f;

  for (int kt = kt0; kt < kt1; ++kt) {
    const int key0 = kt * 64;
    const bool diag = (kt == nb - 1);
    const int tmax = diag ? (j & 3) : 3;

    // V^T fragments: issue early, consumed after softmax.
    bf16x8 av[2][4];
#pragma unroll
    for (int kk2 = 0; kk2 < 2; ++kk2)
#pragma unroll
      for (int dt = 0; dt < 4; ++dt)
        av[kk2][dt] = *(const bf16x8*)(vb + (long)(dt * 16 + lo) * 2048 + key0 +
                                       kk2 * 32 + quad * 8);

    // S^T = K Q^T
    f32x4 s[4];
#pragma unroll
    for (int t = 0; t < 4; ++t) {
      if (t <= tmax) {
        const unsigned short* kr = kb + (long)(key0 + t * 16 + lo) * 64 + quad * 8;
        bf16x8 ak0 = *(const bf16x8*)kr;
        bf16x8 ak1 = *(const bf16x8*)(kr + 32);
        s[t] = (f32x4){0.f, 0.f, 0.f, 0.f};
        s[t] = mfma16(ak0, bq0, s[t]);
        s[t] = mfma16(ak1, bq1, s[t]);
      } else {
        s[t] = (f32x4){NEG_INF, NEG_INF, NEG_INF, NEG_INF};
      }
    }
    if (diag) {
      const int qrl = qrow0 + lo;
#pragma unroll
      for (int t = 0; t < 4; ++t)
#pragma unroll
        for (int r = 0; r < 4; ++r)
          if (key0 + t * 16 + quad * 4 + r > qrl) s[t][r] = NEG_INF;
    }
    // softmax without max-subtraction (logits bounded; exp2 of -inf -> 0)
    float psum = 0.f;
#pragma unroll
    for (int t = 0; t < 4; ++t)
#pragma unroll
      for (int r = 0; r < 4; ++r) {
        float p = exp2f(s[t][r] * Cs);
        s[t][r] = p;
        psum += p;
      }
    l += psum;

    // P^T (C-layout) -> ps[qrow][key], wave-private, no barrier
#pragma unroll
    for (int t = 0; t < 4; ++t) {
      ushort4 pk;
      pk.x = f2bf(s[t][0]); pk.y = f2bf(s[t][1]);
      pk.z = f2bf(s[t][2]); pk.w = f2bf(s[t][3]);
      *(ushort4*)&ps[wave][lo][t * 16 + quad * 4] = pk;
    }
    asm volatile("s_waitcnt lgkmcnt(0)" ::: "memory");
    // O^T += V^T P^T
#pragma unroll
    for (int kk2 = 0; kk2 < 2; ++kk2) {
      bf16x8 bp = *(const bf16x8*)&ps[wave][lo][kk2 * 32 + quad * 8];
#pragma unroll
      for (int dt = 0; dt < 4; ++dt) oacc[dt] = mfma16(av[kk2][dt], bp, oacc[dt]);
    }
  }

  // ---- split-K merge: pure add (no max state) ----
  if (h == 1) {
#pragma unroll
    for (int dt = 0; dt < 4; ++dt)
      *(f32x4*)&olds[jj][lo][dt * 16 + quad * 4] = oacc[dt];
  }
  llds[jj][h][quad][lo] = l;
  __syncthreads();
  if (h == 0) {
    float lt = 0.f;
#pragma unroll
    for (int hh = 0; hh < 2; ++hh)
#pragma unroll
      for (int q = 0; q < 4; ++q) lt += llds[jj][hh][q][lo];
    const float inv = 1.0f / lt;
    float* orow = ob + (long)(qrow0 + lo) * 64;
#pragma unroll
    for (int dt = 0; dt < 4; ++dt) {
      f32x4 o2 = *(const f32x4*)&olds[jj][lo][dt * 16 + quad * 4];
      float4 st;
      st.x = (oacc[dt][0] + o2[0]) * inv;
      st.y = (oacc[dt][1] + o2[1]) * inv;
      st.z = (oacc[dt][2] + o2[2]) * inv;
      st.w = (oacc[dt][3] + o2[3]) * inv;
      *(float4*)(orow + dt * 16 + quad * 4) = st;
    }
  }
}

// ---------------- launcher ----------------
extern "C" void kernel_launch(void* const* d_in, const int* in_sizes, int n_in,
                              void* d_out, int out_size, void* d_ws, size_t ws_size,
                              hipStream_t stream) {
  const float* x = (const float*)d_in[0];
  const float* wq = (const float*)d_in[1];
  const float* wk = (const float*)d_in[2];
  const float* wv = (const float*)d_in[3];
  float* out = (float*)d_out;

  char* ws = (char*)d_ws;
  unsigned short* wt = (unsigned short*)ws;  // 192*384*2 = 147456 B
  const size_t qkv_elems = (size_t)16 * 2048 * 64;
  unsigned short* qws = (unsigned short*)(ws + 147456);
  unsigned short* kws = qws + qkv_elems;
  unsigned short* vws = kws + qkv_elems;

  prep_w<<<96, 256, 0, stream>>>(wq, wk, wv, wt);
  proj_kernel<<<1024, 256, 0, stream>>>(x, wt, qws, kws, vws);
  attn_kernel<<<1024, 256, 0, stream>>>(qws, kws, vws, out);
}

// Round 4
// 203.124 us; speedup vs baseline: 1.0687x; 1.0071x over previous
//
#include <hip/hip_runtime.h>

typedef short bf16x8 __attribute__((ext_vector_type(8)));
typedef float f32x4 __attribute__((ext_vector_type(4)));

#define NEG_INF (-__builtin_inff())

static __device__ __forceinline__ unsigned short f2bf(float f) {
  union { float f; unsigned u; } v; v.f = f;
  return (unsigned short)((v.u + 0x7fffu + ((v.u >> 16) & 1u)) >> 16);
}
static __device__ __forceinline__ unsigned fbits(float f) {
  union { float f; unsigned u; } v; v.f = f;
  return v.u;
}
static __device__ __forceinline__ f32x4 mfma16(bf16x8 a, bf16x8 b, f32x4 c) {
  return __builtin_amdgcn_mfma_f32_16x16x32_bf16(a, b, c, 0, 0, 0);
}

// ---------------- kernel 0: W -> W^T bf16 [192][384]; Q rows pre-scaled by 0.125*log2(e)
__global__ __launch_bounds__(256) void prep_w(const float* __restrict__ wq,
                                              const float* __restrict__ wk,
                                              const float* __restrict__ wv,
                                              unsigned short* __restrict__ wt) {
  int i = blockIdx.x * 256 + threadIdx.x;
  if (i >= 384 * 64) return;
  int c = i >> 6, d = i & 63;
  const float Cs = 0.18033688011112042f;  // 0.125 * log2(e) folded into Q
  wt[(long)d * 384 + c] = f2bf(wq[i] * Cs);
  wt[(long)(64 + d) * 384 + c] = f2bf(wk[i]);
  wt[(long)(128 + d) * 384 + c] = f2bf(wv[i]);
}

// ---------------- kernel 1: QKV projection ----------------
// 512 blocks x 4 waves; wave = 16-token m-tile, ALL 12 n-tiles. x frags in
// registers (one HBM read); W frags double-buffered from L2 (prefetch nt+1).
__global__ __launch_bounds__(256, 2) void proj_kernel(
    const float* __restrict__ x, const unsigned short* __restrict__ wt,
    unsigned short* __restrict__ qo, unsigned short* __restrict__ ko,
    unsigned short* __restrict__ vto) {
  const int tid = threadIdx.x;
  const int wave = tid >> 6, lane = tid & 63;
  const int lo = lane & 15, quad = lane >> 4;
  const long tok0 = ((long)blockIdx.x * 4 + wave) * 16;

  bf16x8 ax[12];
  const float* xr = x + (tok0 + lo) * 384 + quad * 8;
#pragma unroll
  for (int kk = 0; kk < 12; ++kk) {
    float4 x0 = *(const float4*)(xr + kk * 32);
    float4 x1 = *(const float4*)(xr + kk * 32 + 4);
    bf16x8 a;
    a[0] = (short)f2bf(x0.x); a[1] = (short)f2bf(x0.y);
    a[2] = (short)f2bf(x0.z); a[3] = (short)f2bf(x0.w);
    a[4] = (short)f2bf(x1.x); a[5] = (short)f2bf(x1.y);
    a[6] = (short)f2bf(x1.z); a[7] = (short)f2bf(x1.w);
    ax[kk] = a;
  }
  const unsigned short* wl = wt + (long)lo * 384 + quad * 8;
  bf16x8 wf[2][12];
#pragma unroll
  for (int kk = 0; kk < 12; ++kk) wf[0][kk] = *(const bf16x8*)(wl + kk * 32);

  const long bb = tok0 >> 11;
  const int tokg = (int)(tok0 & 2047);

#pragma unroll
  for (int nt = 0; nt < 12; ++nt) {
    if (nt < 11) {
      const unsigned short* wn = wl + (long)(nt + 1) * 16 * 384;
#pragma unroll
      for (int kk = 0; kk < 12; ++kk)
        wf[(nt + 1) & 1][kk] = *(const bf16x8*)(wn + kk * 32);
    }
    f32x4 a0 = (f32x4){0.f, 0.f, 0.f, 0.f}, a1 = (f32x4){0.f, 0.f, 0.f, 0.f};
#pragma unroll
    for (int kk = 0; kk < 12; kk += 2) {
      if (nt < 8) {
        a0 = mfma16(ax[kk], wf[nt & 1][kk], a0);      // C[tok][d]
        a1 = mfma16(ax[kk + 1], wf[nt & 1][kk + 1], a1);
      } else {
        a0 = mfma16(wf[nt & 1][kk], ax[kk], a0);      // C[d][tok]  (V transposed)
        a1 = mfma16(wf[nt & 1][kk + 1], ax[kk + 1], a1);
      }
    }
#pragma unroll
    for (int r = 0; r < 4; ++r) {
      float v = a0[r] + a1[r];
      if (nt < 4)
        qo[(tok0 + quad * 4 + r) * 64 + nt * 16 + lo] = f2bf(v);
      else if (nt < 8)
        ko[(tok0 + quad * 4 + r) * 64 + (nt - 4) * 16 + lo] = f2bf(v);
      else
        vto[(bb * 64 + (nt - 8) * 16 + quad * 4 + r) * 2048 + tokg + lo] = f2bf(v);
    }
  }
}

// ---------------- kernel 2: causal flash attention, 4-way split-K ----------------
// 2048 blocks x 4 waves. Block = one q-tile j (16 rows) x batch b; wave h does
// quarter h of the key range. No running max (logits bounded). Merge: LDS add tree.
__global__ __launch_bounds__(256, 6) void attn_kernel(
    const unsigned short* __restrict__ qg, const unsigned short* __restrict__ kg,
    const unsigned short* __restrict__ vg, float* __restrict__ out) {
  __shared__ unsigned short ps[4][16][72];  // wave-private P^T [qrow][key]
  __shared__ float olds[2][16][68];         // partial-O merge buffers
  __shared__ float llds[4][4][16];          // [h][quad][qrow] partial l

  const int tid = threadIdx.x;
  const int h = tid >> 6, lane = tid & 63;
  const int lo = lane & 15, quad = lane >> 4;
  const int b = blockIdx.x & 15;
  const int j = 127 - (blockIdx.x >> 4);    // biggest q-tiles first
  const int nb = (j >> 2) + 1;
  const int base = nb >> 2, rem = nb & 3;
  const int kt0 = h * base + (h < rem ? h : rem);
  const int kt1 = kt0 + base + (h < rem ? 1 : 0);
  const int qrow0 = j * 16;

  const unsigned short* qb = qg + (long)b * 2048 * 64;
  const unsigned short* kb = kg + (long)b * 2048 * 64;
  const unsigned short* vb = vg + (long)b * 64 * 2048;  // [64][2048]
  float* ob = out + (long)b * 2048 * 64;

  const unsigned short* qr = qb + (long)(qrow0 + lo) * 64 + quad * 8;
  const bf16x8 bq0 = *(const bf16x8*)qr;   // Q pre-scaled by 0.125*log2(e)
  const bf16x8 bq1 = *(const bf16x8*)(qr + 32);

  f32x4 oacc[4];
#pragma unroll
  for (int dt = 0; dt < 4; ++dt) oacc[dt] = (f32x4){0.f, 0.f, 0.f, 0.f};
  float l = 0.f;

  for (int kt = kt0; kt < kt1; ++kt) {
    const int key0 = kt * 64;
    const bool diag = (kt == nb - 1);
    const int tmax = diag ? (j & 3) : 3;

    // V^T fragments: issue first, consumed after softmax (latency hidden by QK+softmax)
    bf16x8 av[2][4];
#pragma unroll
    for (int kk2 = 0; kk2 < 2; ++kk2)
#pragma unroll
      for (int dt = 0; dt < 4; ++dt)
        av[kk2][dt] = *(const bf16x8*)(vb + (long)(dt * 16 + lo) * 2048 + key0 +
                                       kk2 * 32 + quad * 8);

    // per-16-key strip: QK -> exp2 -> pack -> LDS (no cross-strip state needed)
#pragma unroll
    for (int t = 0; t < 4; ++t) {
      if (t <= tmax) {
        const unsigned short* kr = kb + (long)(key0 + t * 16 + lo) * 64 + quad * 8;
        bf16x8 ak0 = *(const bf16x8*)kr;
        bf16x8 ak1 = *(const bf16x8*)(kr + 32);
        f32x4 s = (f32x4){0.f, 0.f, 0.f, 0.f};
        s = mfma16(ak0, bq0, s);
        s = mfma16(ak1, bq1, s);
        if (diag) {
          const int qrl = qrow0 + lo;
#pragma unroll
          for (int r = 0; r < 4; ++r)
            if (key0 + t * 16 + quad * 4 + r > qrl) s[r] = NEG_INF;
        }
        float e0 = __builtin_amdgcn_exp2f(s[0]);
        float e1 = __builtin_amdgcn_exp2f(s[1]);
        float e2 = __builtin_amdgcn_exp2f(s[2]);
        float e3 = __builtin_amdgcn_exp2f(s[3]);
        l += (e0 + e1) + (e2 + e3);
        // pack pairs to bf16 (round-half-up) via v_perm
        unsigned u0 = __builtin_amdgcn_perm(fbits(e1) + 0x8000u, fbits(e0) + 0x8000u,
                                            0x07060302u);
        unsigned u1 = __builtin_amdgcn_perm(fbits(e3) + 0x8000u, fbits(e2) + 0x8000u,
                                            0x07060302u);
        uint2 uu; uu.x = u0; uu.y = u1;
        *(uint2*)&ps[h][lo][t * 16 + quad * 4] = uu;
      } else {
        uint2 zz; zz.x = 0u; zz.y = 0u;
        *(uint2*)&ps[h][lo][t * 16 + quad * 4] = zz;
      }
    }
    asm volatile("s_waitcnt lgkmcnt(0)" ::: "memory");  // wave-private, no barrier
    // O^T += V^T P^T
#pragma unroll
    for (int kk2 = 0; kk2 < 2; ++kk2) {
      bf16x8 bp = *(const bf16x8*)&ps[h][lo][kk2 * 32 + quad * 8];
#pragma unroll
      for (int dt = 0; dt < 4; ++dt) oacc[dt] = mfma16(av[kk2][dt], bp, oacc[dt]);
    }
  }

  // ---- merge (pure adds): h2->buf0, h3->buf1; h0+=buf0, h1+=buf1; h1->buf1; h0+=buf1
  if (h >= 2) {
#pragma unroll
    for (int dt = 0; dt < 4; ++dt)
      *(f32x4*)&olds[h - 2][lo][dt * 16 + quad * 4] = oacc[dt];
  }
  llds[h][quad][lo] = l;
  __syncthreads();
  if (h < 2) {
#pragma unroll
    for (int dt = 0; dt < 4; ++dt) {
      f32x4 o2 = *(const f32x4*)&olds[h][lo][dt * 16 + quad * 4];
      oacc[dt] += o2;
    }
    if (h == 1) {
#pragma unroll
      for (int dt = 0; dt < 4; ++dt)
        *(f32x4*)&olds[1][lo][dt * 16 + quad * 4] = oacc[dt];
    }
  }
  __syncthreads();
  if (h == 0) {
    float lt = 0.f;
#pragma unroll
    for (int hh = 0; hh < 4; ++hh)
#pragma unroll
      for (int q = 0; q < 4; ++q) lt += llds[hh][q][lo];
    const float inv = 1.0f / lt;
    float* orow = ob + (long)(qrow0 + lo) * 64;
#pragma unroll
    for (int dt = 0; dt < 4; ++dt) {
      f32x4 o2 = *(const f32x4*)&olds[1][lo][dt * 16 + quad * 4];
      float4 st;
      st.x = (oacc[dt][0] + o2[0]) * inv;
      st.y = (oacc[dt][1] + o2[1]) * inv;
      st.z = (oacc[dt][2] + o2[2]) * inv;
      st.w = (oacc[dt][3] + o2[3]) * inv;
      *(float4*)(orow + dt * 16 + quad * 4) = st;
    }
  }
}

// ---------------- launcher ----------------
extern "C" void kernel_launch(void* const* d_in, const int* in_sizes, int n_in,
                              void* d_out, int out_size, void* d_ws, size_t ws_size,
                              hipStream_t stream) {
  const float* x = (const float*)d_in[0];
  const float* wq = (const float*)d_in[1];
  const float* wk = (const float*)d_in[2];
  const float* wv = (const float*)d_in[3];
  float* out = (float*)d_out;

  char* ws = (char*)d_ws;
  unsigned short* wt = (unsigned short*)ws;  // 192*384*2 = 147456 B
  const size_t qkv_elems = (size_t)16 * 2048 * 64;
  unsigned short* qws = (unsigned short*)(ws + 147456);
  unsigned short* kws = qws + qkv_elems;
  unsigned short* vws = kws + qkv_elems;

  prep_w<<<96, 256, 0, stream>>>(wq, wk, wv, wt);
  proj_kernel<<<512, 256, 0, stream>>>(x, wt, qws, kws, vws);
  attn_kernel<<<2048, 256, 0, stream>>>(qws, kws, vws, out);
}

// Round 5
// 198.522 us; speedup vs baseline: 1.0934x; 1.0232x over previous
//
#include <hip/hip_runtime.h>

typedef short bf16x8 __attribute__((ext_vector_type(8)));
typedef float f32x4 __attribute__((ext_vector_type(4)));

#define NEG_INF (-__builtin_inff())

static __device__ __forceinline__ unsigned short f2bf(float f) {
  union { float f; unsigned u; } v; v.f = f;
  return (unsigned short)((v.u + 0x7fffu + ((v.u >> 16) & 1u)) >> 16);
}
static __device__ __forceinline__ unsigned fbits(float f) {
  union { float f; unsigned u; } v; v.f = f;
  return v.u;
}
static __device__ __forceinline__ f32x4 mfma16(bf16x8 a, bf16x8 b, f32x4 c) {
  return __builtin_amdgcn_mfma_f32_16x16x32_bf16(a, b, c, 0, 0, 0);
}

// ---------------- kernel 0: W -> W^T bf16 [192][384]; Q rows pre-scaled by 0.125*log2(e)
__global__ __launch_bounds__(256) void prep_w(const float* __restrict__ wq,
                                              const float* __restrict__ wk,
                                              const float* __restrict__ wv,
                                              unsigned short* __restrict__ wt) {
  int i = blockIdx.x * 256 + threadIdx.x;
  if (i >= 384 * 64) return;
  int c = i >> 6, d = i & 63;
  const float Cs = 0.18033688011112042f;  // 0.125 * log2(e) folded into Q
  wt[(long)d * 384 + c] = f2bf(wq[i] * Cs);
  wt[(long)(64 + d) * 384 + c] = f2bf(wk[i]);
  wt[(long)(128 + d) * 384 + c] = f2bf(wv[i]);
}

// ---------------- kernel 1: QKV projection ----------------
// 512 blocks x 4 waves; wave = 16-token m-tile, ALL 12 n-tiles. x frags in
// registers (one HBM read); W frags double-buffered from L2 (prefetch nt+1).
__global__ __launch_bounds__(256, 2) void proj_kernel(
    const float* __restrict__ x, const unsigned short* __restrict__ wt,
    unsigned short* __restrict__ qo, unsigned short* __restrict__ ko,
    unsigned short* __restrict__ vto) {
  const int tid = threadIdx.x;
  const int wave = tid >> 6, lane = tid & 63;
  const int lo = lane & 15, quad = lane >> 4;
  const long tok0 = ((long)blockIdx.x * 4 + wave) * 16;

  bf16x8 ax[12];
  const float* xr = x + (tok0 + lo) * 384 + quad * 8;
#pragma unroll
  for (int kk = 0; kk < 12; ++kk) {
    float4 x0 = *(const float4*)(xr + kk * 32);
    float4 x1 = *(const float4*)(xr + kk * 32 + 4);
    bf16x8 a;
    a[0] = (short)f2bf(x0.x); a[1] = (short)f2bf(x0.y);
    a[2] = (short)f2bf(x0.z); a[3] = (short)f2bf(x0.w);
    a[4] = (short)f2bf(x1.x); a[5] = (short)f2bf(x1.y);
    a[6] = (short)f2bf(x1.z); a[7] = (short)f2bf(x1.w);
    ax[kk] = a;
  }
  const unsigned short* wl = wt + (long)lo * 384 + quad * 8;
  bf16x8 wf[2][12];
#pragma unroll
  for (int kk = 0; kk < 12; ++kk) wf[0][kk] = *(const bf16x8*)(wl + kk * 32);

  const long bb = tok0 >> 11;
  const int tokg = (int)(tok0 & 2047);

#pragma unroll
  for (int nt = 0; nt < 12; ++nt) {
    if (nt < 11) {
      const unsigned short* wn = wl + (long)(nt + 1) * 16 * 384;
#pragma unroll
      for (int kk = 0; kk < 12; ++kk)
        wf[(nt + 1) & 1][kk] = *(const bf16x8*)(wn + kk * 32);
    }
    f32x4 a0 = (f32x4){0.f, 0.f, 0.f, 0.f}, a1 = (f32x4){0.f, 0.f, 0.f, 0.f};
#pragma unroll
    for (int kk = 0; kk < 12; kk += 2) {
      if (nt < 8) {
        a0 = mfma16(ax[kk], wf[nt & 1][kk], a0);      // C[tok][d]
        a1 = mfma16(ax[kk + 1], wf[nt & 1][kk + 1], a1);
      } else {
        a0 = mfma16(wf[nt & 1][kk], ax[kk], a0);      // C[d][tok]  (V transposed)
        a1 = mfma16(wf[nt & 1][kk + 1], ax[kk + 1], a1);
      }
    }
#pragma unroll
    for (int r = 0; r < 4; ++r) {
      float v = a0[r] + a1[r];
      if (nt < 4)
        qo[(tok0 + quad * 4 + r) * 64 + nt * 16 + lo] = f2bf(v);
      else if (nt < 8)
        ko[(tok0 + quad * 4 + r) * 64 + (nt - 4) * 16 + lo] = f2bf(v);
      else
        vto[(bb * 64 + (nt - 8) * 16 + quad * 4 + r) * 2048 + tokg + lo] = f2bf(v);
    }
  }
}

// ---------------- kernel 2: causal flash attention, 4-way split-K, reg-prefetch ----
// 2048 blocks x 4 waves. Block = one q-tile j x batch b; wave h does quarter h of
// the key range. Per iteration: batch-issue 8 K loads (current) + 8 V loads (next)
// -> ~16 outstanding 1KB loads/wave (fixes the MLP=1 serialization seen at R4's
// VGPR_Count=40). launch_bounds(256,3) gives the register budget (~150 live).
__global__ __launch_bounds__(256, 3) void attn_kernel(
    const unsigned short* __restrict__ qg, const unsigned short* __restrict__ kg,
    const unsigned short* __restrict__ vg, float* __restrict__ out) {
  __shared__ unsigned short ps[4][16][72];  // wave-private P^T [qrow][key]
  __shared__ float olds[2][16][68];         // partial-O merge buffers
  __shared__ float llds[4][4][16];          // [h][quad][qrow] partial l

  const int tid = threadIdx.x;
  const int h = tid >> 6, lane = tid & 63;
  const int lo = lane & 15, quad = lane >> 4;
  const int b = blockIdx.x & 15;
  const int j = 127 - (blockIdx.x >> 4);    // biggest q-tiles first
  const int nb = (j >> 2) + 1;
  const int base = nb >> 2, rem = nb & 3;
  const int kt0 = h * base + (h < rem ? h : rem);
  const int kt1 = kt0 + base + (h < rem ? 1 : 0);
  const int qrow0 = j * 16;

  const unsigned short* qb = qg + (long)b * 2048 * 64;
  const unsigned short* kb = kg + (long)b * 2048 * 64;
  const unsigned short* vb = vg + (long)b * 64 * 2048;  // [64][2048]
  float* ob = out + (long)b * 2048 * 64;

  const unsigned short* qr = qb + (long)(qrow0 + lo) * 64 + quad * 8;
  const bf16x8 bq0 = *(const bf16x8*)qr;   // Q pre-scaled by 0.125*log2(e)
  const bf16x8 bq1 = *(const bf16x8*)(qr + 32);

  // per-lane V base: row = dt*16+lo (row stride 2048), col offset kk2*32+quad*8
  const unsigned short* vl = vb + (long)lo * 2048 + quad * 8;

  f32x4 oacc[4];
#pragma unroll
  for (int dt = 0; dt < 4; ++dt) oacc[dt] = (f32x4){0.f, 0.f, 0.f, 0.f};
  float l = 0.f;

  // prologue: V fragments for kt0 (clamped so empty waves read safely)
  bf16x8 av[2][4];
  {
    const int key0p = (kt0 < kt1) ? kt0 * 64 : 0;
#pragma unroll
    for (int kk2 = 0; kk2 < 2; ++kk2)
#pragma unroll
      for (int dt = 0; dt < 4; ++dt)
        av[kk2][dt] = *(const bf16x8*)(vl + (long)dt * 16 * 2048 + key0p + kk2 * 32);
  }

  for (int kt = kt0; kt < kt1; ++kt) {
    const int key0 = kt * 64;
    const bool diag = (kt == nb - 1);

    // batch-issue current K (8 independent 1KB loads)
    bf16x8 ak0[4], ak1[4];
#pragma unroll
    for (int t = 0; t < 4; ++t) {
      const unsigned short* kr = kb + (long)(key0 + t * 16 + lo) * 64 + quad * 8;
      ak0[t] = *(const bf16x8*)kr;
      ak1[t] = *(const bf16x8*)(kr + 32);
    }
    // prefetch next-iteration V (8 more loads in flight; clamp on last iter)
    bf16x8 avn[2][4];
    {
      const int keyn = ((kt + 1 < kt1) ? kt + 1 : kt) * 64;
#pragma unroll
      for (int kk2 = 0; kk2 < 2; ++kk2)
#pragma unroll
        for (int dt = 0; dt < 4; ++dt)
          avn[kk2][dt] = *(const bf16x8*)(vl + (long)dt * 16 * 2048 + keyn + kk2 * 32);
    }

    // per-16-key strip: QK -> mask -> exp2 -> pack -> LDS (uniform, no branches)
#pragma unroll
    for (int t = 0; t < 4; ++t) {
      f32x4 s = (f32x4){0.f, 0.f, 0.f, 0.f};
      s = mfma16(ak0[t], bq0, s);
      s = mfma16(ak1[t], bq1, s);
      if (diag) {
        const int qrl = qrow0 + lo;
#pragma unroll
        for (int r = 0; r < 4; ++r)
          if (key0 + t * 16 + quad * 4 + r > qrl) s[r] = NEG_INF;
      }
      float e0 = __builtin_amdgcn_exp2f(s[0]);
      float e1 = __builtin_amdgcn_exp2f(s[1]);
      float e2 = __builtin_amdgcn_exp2f(s[2]);
      float e3 = __builtin_amdgcn_exp2f(s[3]);
      l += (e0 + e1) + (e2 + e3);
      unsigned u0 = __builtin_amdgcn_perm(fbits(e1) + 0x8000u, fbits(e0) + 0x8000u,
                                          0x07060302u);
      unsigned u1 = __builtin_amdgcn_perm(fbits(e3) + 0x8000u, fbits(e2) + 0x8000u,
                                          0x07060302u);
      uint2 uu; uu.x = u0; uu.y = u1;
      *(uint2*)&ps[h][lo][t * 16 + quad * 4] = uu;
    }
    asm volatile("s_waitcnt lgkmcnt(0)" ::: "memory");  // wave-private, no barrier
    // O^T += V^T P^T  (av was prefetched last iteration)
#pragma unroll
    for (int kk2 = 0; kk2 < 2; ++kk2) {
      bf16x8 bp = *(const bf16x8*)&ps[h][lo][kk2 * 32 + quad * 8];
#pragma unroll
      for (int dt = 0; dt < 4; ++dt) oacc[dt] = mfma16(av[kk2][dt], bp, oacc[dt]);
    }
    // rotate prefetch buffer
#pragma unroll
    for (int kk2 = 0; kk2 < 2; ++kk2)
#pragma unroll
      for (int dt = 0; dt < 4; ++dt) av[kk2][dt] = avn[kk2][dt];
  }

  // ---- merge (pure adds): h2->buf0, h3->buf1; h0+=buf0, h1+=buf1; h1->buf1; h0+=buf1
  if (h >= 2) {
#pragma unroll
    for (int dt = 0; dt < 4; ++dt)
      *(f32x4*)&olds[h - 2][lo][dt * 16 + quad * 4] = oacc[dt];
  }
  llds[h][quad][lo] = l;
  __syncthreads();
  if (h < 2) {
#pragma unroll
    for (int dt = 0; dt < 4; ++dt) {
      f32x4 o2 = *(const f32x4*)&olds[h][lo][dt * 16 + quad * 4];
      oacc[dt] += o2;
    }
    if (h == 1) {
#pragma unroll
      for (int dt = 0; dt < 4; ++dt)
        *(f32x4*)&olds[1][lo][dt * 16 + quad * 4] = oacc[dt];
    }
  }
  __syncthreads();
  if (h == 0) {
    float lt = 0.f;
#pragma unroll
    for (int hh = 0; hh < 4; ++hh)
#pragma unroll
      for (int q = 0; q < 4; ++q) lt += llds[hh][q][lo];
    const float inv = 1.0f / lt;
    float* orow = ob + (long)(qrow0 + lo) * 64;
#pragma unroll
    for (int dt = 0; dt < 4; ++dt) {
      f32x4 o2 = *(const f32x4*)&olds[1][lo][dt * 16 + quad * 4];
      float4 st;
      st.x = (oacc[dt][0] + o2[0]) * inv;
      st.y = (oacc[dt][1] + o2[1]) * inv;
      st.z = (oacc[dt][2] + o2[2]) * inv;
      st.w = (oacc[dt][3] + o2[3]) * inv;
      *(float4*)(orow + dt * 16 + quad * 4) = st;
    }
  }
}

// ---------------- launcher ----------------
extern "C" void kernel_launch(void* const* d_in, const int* in_sizes, int n_in,
                              void* d_out, int out_size, void* d_ws, size_t ws_size,
                              hipStream_t stream) {
  const float* x = (const float*)d_in[0];
  const float* wq = (const float*)d_in[1];
  const float* wk = (const float*)d_in[2];
  const float* wv = (const float*)d_in[3];
  float* out = (float*)d_out;

  char* ws = (char*)d_ws;
  unsigned short* wt = (unsigned short*)ws;  // 192*384*2 = 147456 B
  const size_t qkv_elems = (size_t)16 * 2048 * 64;
  unsigned short* qws = (unsigned short*)(ws + 147456);
  unsigned short* kws = qws + qkv_elems;
  unsigned short* vws = kws + qkv_elems;

  prep_w<<<96, 256, 0, stream>>>(wq, wk, wv, wt);
  proj_kernel<<<512, 256, 0, stream>>>(x, wt, qws, kws, vws);
  attn_kernel<<<2048, 256, 0, stream>>>(qws, kws, vws, out);
}

// Round 7
// 128.295 us; speedup vs baseline: 1.6920x; 1.5474x over previous
//
#include <hip/hip_runtime.h>

typedef short bf16x8 __attribute__((ext_vector_type(8)));
typedef float f32x4 __attribute__((ext_vector_type(4)));
typedef unsigned int u32;
typedef __attribute__((address_space(1))) const u32 gu32;
typedef __attribute__((address_space(3))) u32 lu32;

#define NEG_INF (-__builtin_inff())

static __device__ __forceinline__ unsigned short f2bf(float f) {
  union { float f; unsigned u; } v; v.f = f;
  return (unsigned short)((v.u + 0x7fffu + ((v.u >> 16) & 1u)) >> 16);
}
static __device__ __forceinline__ unsigned fbits(float f) {
  union { float f; unsigned u; } v; v.f = f;
  return v.u;
}
static __device__ __forceinline__ f32x4 mfma16(bf16x8 a, bf16x8 b, f32x4 c) {
  return __builtin_amdgcn_mfma_f32_16x16x32_bf16(a, b, c, 0, 0, 0);
}
// async DMA: 64 lanes x 16B -> contiguous 1KB LDS at (uniform) l + lane*16
static __device__ __forceinline__ void dma16(const void* g, void* l) {
  __builtin_amdgcn_global_load_lds((gu32*)g, (lu32*)l, 16, 0, 0);
}

// ---------------- kernel 0: W -> swizzled-tiled W^T chunks ----------------
// layout: [chunk c6=c>>6][row dd (0..191: Q,K,V x 64)][64 c], byte =
// (c6*192+dd)*128 + ((cin*2) ^ ((dd&7)<<4)).  Q rows pre-scaled by 0.125*log2(e).
__global__ __launch_bounds__(256) void prep_w(const float* __restrict__ wq,
                                              const float* __restrict__ wk,
                                              const float* __restrict__ wv,
                                              char* __restrict__ wt) {
  int i = blockIdx.x * 256 + threadIdx.x;
  if (i >= 384 * 64) return;
  int c = i >> 6, d = i & 63;
  int c6 = c >> 6, cin = c & 63;
  const float Cs = 0.18033688011112042f;
  long base = (long)(c6 * 192) * 128;
  int col = (cin * 2) ^ ((d & 7) << 4);
  *(unsigned short*)(wt + base + (long)d * 128 + col) = f2bf(wq[i] * Cs);
  *(unsigned short*)(wt + base + (long)(64 + d) * 128 + col) = f2bf(wk[i]);
  *(unsigned short*)(wt + base + (long)(128 + d) * 128 + col) = f2bf(wv[i]);
}

// ---------------- kernel 1: QKV projection ----------------
// 512 blocks x 4 waves (64 tokens/block, 16/wave). W staged to LDS by 24KB
// chunks via global_load_lds (double-buffered); x held in registers.
// All MFMAs are mfma16(axk, wf): C[m=token(quad*4+r)][n=row-of-W (lo)].
// Outputs: Q plain [tok][64]; K tiled-swizzled [b][kt][key][64d];
// V^T tiled-swizzled [b][kt][d][64key].
__global__ __launch_bounds__(256, 2) void proj_kernel(
    const float* __restrict__ x, const char* __restrict__ wt,
    unsigned short* __restrict__ qo, char* __restrict__ kT,
    char* __restrict__ vT) {
  __shared__ char wls[2][24576];
  const int tid = threadIdx.x;
  const int wave = tid >> 6, lane = tid & 63;
  const int lo = lane & 15, quad = lane >> 4;
  const long tok0 = ((long)blockIdx.x * 4 + wave) * 16;

  // prologue: DMA chunk 0 (24 segs of 1KB; wave issues segs wave*6..wave*6+5)
#pragma unroll
  for (int s2 = 0; s2 < 6; ++s2) {
    const int s = wave * 6 + s2;
    dma16(wt + s * 1024 + lane * 16, &wls[0][s * 1024]);
  }
  // x fragments -> registers (the only HBM read)
  bf16x8 ax[12];
  const float* xr = x + (tok0 + lo) * 384 + quad * 8;
#pragma unroll
  for (int kk = 0; kk < 12; ++kk) {
    float4 x0 = *(const float4*)(xr + kk * 32);
    float4 x1 = *(const float4*)(xr + kk * 32 + 4);
    bf16x8 a;
    a[0] = (short)f2bf(x0.x); a[1] = (short)f2bf(x0.y);
    a[2] = (short)f2bf(x0.z); a[3] = (short)f2bf(x0.w);
    a[4] = (short)f2bf(x1.x); a[5] = (short)f2bf(x1.y);
    a[6] = (short)f2bf(x1.z); a[7] = (short)f2bf(x1.w);
    ax[kk] = a;
  }

  f32x4 acc[12];
#pragma unroll
  for (int nt = 0; nt < 12; ++nt) acc[nt] = (f32x4){0.f, 0.f, 0.f, 0.f};

  for (int c6 = 0; c6 < 6; ++c6) {
    const int buf = c6 & 1;
    __syncthreads();                       // chunk c6 resident; buf^1 free
    if (c6 < 5) {
      const char* wg = wt + (long)(c6 + 1) * 24576;
#pragma unroll
      for (int s2 = 0; s2 < 6; ++s2) {
        const int s = wave * 6 + s2;
        dma16(wg + s * 1024 + lane * 16, &wls[buf ^ 1][s * 1024]);
      }
    }
#pragma unroll
    for (int kk = 0; kk < 2; ++kk) {
      const bf16x8 axk = ax[c6 * 2 + kk];
#pragma unroll
      for (int nt = 0; nt < 12; ++nt) {
        const int dd = nt * 16 + lo;
        const int col = ((kk * 4 + quad) ^ (lo & 7)) << 4;
        bf16x8 wf = *(const bf16x8*)(&wls[buf][dd * 128 + col]);
        acc[nt] = mfma16(axk, wf, acc[nt]);   // C[tok][w-row]
      }
    }
  }

  // epilogue (all acc: m=token=quad*4+r, n=lo)
  const long bb = tok0 >> 11;
  const int tin0 = (int)(tok0 & 2047);
  const int kt = tin0 >> 6;
  const long tile = ((bb * 32 + kt) << 13);  // 8192 B per tile
  const int key0w = (tin0 & 63) + quad * 4;  // token_local of acc rows r=0..3
#pragma unroll
  for (int nt = 0; nt < 12; ++nt) {
    if (nt < 4) {
      const int d = nt * 16 + lo;
#pragma unroll
      for (int r = 0; r < 4; ++r)
        qo[(tok0 + quad * 4 + r) * 64 + d] = f2bf(acc[nt][r]);
    } else if (nt < 8) {
      const int d = (nt - 4) * 16 + lo;
#pragma unroll
      for (int r = 0; r < 4; ++r) {
        const int key = key0w + r;
        *(unsigned short*)(kT + tile + key * 128 + (((d * 2) ^ ((key & 7) << 4)))) =
            f2bf(acc[nt][r]);
      }
    } else {
      // V^T row d = (nt-8)*16 + lo; cols = tokens key0w..key0w+3 (r runs over m)
      const int d = (nt - 8) * 16 + lo;
      ushort4 pk;
      pk.x = f2bf(acc[nt][0]); pk.y = f2bf(acc[nt][1]);
      pk.z = f2bf(acc[nt][2]); pk.w = f2bf(acc[nt][3]);
      *(ushort4*)(vT + tile + d * 128 + (((key0w * 2) ^ ((d & 7) << 4)))) = pk;
    }
  }
}

// ---------------- kernel 2: causal flash attention, shared-LDS K/V ----------------
// 512 blocks x 4 waves. Block = (64-q-row group a, batch b); wave w owns q-tile
// j=4a+w. All waves share the same a+1 key tiles, DMA'd to LDS double-buffered.
// Pairing: blocks i and i+256 have a-sums 31 (uniform per-CU load).
__global__ __launch_bounds__(256, 2) void attn_kernel(
    const unsigned short* __restrict__ qg, const char* __restrict__ kT,
    const char* __restrict__ vT, float* __restrict__ out) {
  __shared__ char kls[2][8192];
  __shared__ char vls[2][8192];
  __shared__ unsigned short ps[4][16][72];  // wave-private P^T [qrow][key]

  const int tid = threadIdx.x;
  const int h = tid >> 6, lane = tid & 63;
  const int lo = lane & 15, quad = lane >> 4;
  const int b = blockIdx.x & 15;
  const int idx = blockIdx.x >> 4;
  const int a = (blockIdx.x < 256) ? (31 - idx) : (idx - 16);
  const int j = 4 * a + h;
  const int niter = a + 1;
  const int qrow0 = j * 16;

  const unsigned short* qb = qg + (long)b * 2048 * 64;
  const char* kbT = kT + ((long)b * 32 << 13);
  const char* vbT = vT + ((long)b * 32 << 13);
  float* ob = out + (long)b * 2048 * 64;

  // Q fragments (B-operand), pre-scaled by 0.125*log2(e)
  const unsigned short* qr = qb + (long)(qrow0 + lo) * 64 + quad * 8;
  const bf16x8 bq0 = *(const bf16x8*)qr;
  const bf16x8 bq1 = *(const bf16x8*)(qr + 32);

  // prologue DMA: tile 0 -> buf 0 (wave h issues segs 2h, 2h+1 of K and V)
#pragma unroll
  for (int s2 = 0; s2 < 2; ++s2) {
    const int s = h * 2 + s2;
    dma16(kbT + s * 1024 + lane * 16, &kls[0][s * 1024]);
    dma16(vbT + s * 1024 + lane * 16, &vls[0][s * 1024]);
  }

  f32x4 oacc[4];
#pragma unroll
  for (int dt = 0; dt < 4; ++dt) oacc[dt] = (f32x4){0.f, 0.f, 0.f, 0.f};
  float l = 0.f;

  for (int kt = 0; kt < niter; ++kt) {
    const int buf = kt & 1;
    __syncthreads();  // tile kt resident (vmcnt drained); buf^1 consumers done
    if (kt + 1 < niter) {
      const char* kg = kbT + ((long)(kt + 1) << 13);
      const char* vg = vbT + ((long)(kt + 1) << 13);
#pragma unroll
      for (int s2 = 0; s2 < 2; ++s2) {
        const int s = h * 2 + s2;
        dma16(kg + s * 1024 + lane * 16, &kls[buf ^ 1][s * 1024]);
        dma16(vg + s * 1024 + lane * 16, &vls[buf ^ 1][s * 1024]);
      }
    }
    const bool diag = (kt == niter - 1);
    const int key0 = kt * 64;
    const int swz = (lo & 7);

    // per-16-key strip: QK -> mask -> exp2 -> pack -> ps
#pragma unroll
    for (int t = 0; t < 4; ++t) {
      const int row = (t * 16 + lo) * 128;
      bf16x8 ak0 = *(const bf16x8*)(&kls[buf][row + ((quad ^ swz) << 4)]);
      bf16x8 ak1 = *(const bf16x8*)(&kls[buf][row + (((4 + quad) ^ swz) << 4)]);
      f32x4 s = (f32x4){0.f, 0.f, 0.f, 0.f};
      s = mfma16(ak0, bq0, s);
      s = mfma16(ak1, bq1, s);
      if (diag) {
        const int qrl = qrow0 + lo;
#pragma unroll
        for (int r = 0; r < 4; ++r)
          if (key0 + t * 16 + quad * 4 + r > qrl) s[r] = NEG_INF;
      }
      float e0 = __builtin_amdgcn_exp2f(s[0]);
      float e1 = __builtin_amdgcn_exp2f(s[1]);
      float e2 = __builtin_amdgcn_exp2f(s[2]);
      float e3 = __builtin_amdgcn_exp2f(s[3]);
      l += (e0 + e1) + (e2 + e3);
      unsigned u0 = __builtin_amdgcn_perm(fbits(e1) + 0x8000u, fbits(e0) + 0x8000u,
                                          0x07060302u);
      unsigned u1 = __builtin_amdgcn_perm(fbits(e3) + 0x8000u, fbits(e2) + 0x8000u,
                                          0x07060302u);
      uint2 uu; uu.x = u0; uu.y = u1;
      *(uint2*)&ps[h][lo][t * 16 + quad * 4] = uu;
    }
    asm volatile("s_waitcnt lgkmcnt(0)" ::: "memory");  // wave-private ps
    // O^T += V^T P^T
#pragma unroll
    for (int kk2 = 0; kk2 < 2; ++kk2) {
      bf16x8 bp = *(const bf16x8*)&ps[h][lo][kk2 * 32 + quad * 8];
#pragma unroll
      for (int dt = 0; dt < 4; ++dt) {
        const int rowv = (dt * 16 + lo) * 128;
        bf16x8 av = *(const bf16x8*)(&vls[buf][rowv + (((kk2 * 4 + quad) ^ swz) << 4)]);
        oacc[dt] = mfma16(av, bp, oacc[dt]);
      }
    }
  }

  // epilogue: per-wave complete rows — reduce l over quads, normalize, store
  l += __shfl_xor(l, 16, 64);
  l += __shfl_xor(l, 32, 64);
  const float inv = 1.0f / l;
  float* orow = ob + (long)(qrow0 + lo) * 64;
#pragma unroll
  for (int dt = 0; dt < 4; ++dt) {
    float4 st;
    st.x = oacc[dt][0] * inv; st.y = oacc[dt][1] * inv;
    st.z = oacc[dt][2] * inv; st.w = oacc[dt][3] * inv;
    *(float4*)(orow + dt * 16 + quad * 4) = st;
  }
}

// ---------------- launcher ----------------
extern "C" void kernel_launch(void* const* d_in, const int* in_sizes, int n_in,
                              void* d_out, int out_size, void* d_ws, size_t ws_size,
                              hipStream_t stream) {
  const float* x = (const float*)d_in[0];
  const float* wq = (const float*)d_in[1];
  const float* wk = (const float*)d_in[2];
  const float* wv = (const float*)d_in[3];
  float* out = (float*)d_out;

  char* ws = (char*)d_ws;
  char* wt = ws;                                   // 147456 B (6 chunks x 24576)
  const size_t MB4 = (size_t)4 * 1024 * 1024;      // 16*2048*64*2 bytes
  unsigned short* qws = (unsigned short*)(ws + 147456);
  char* kT = ws + 147456 + MB4;
  char* vT = ws + 147456 + 2 * MB4;

  prep_w<<<96, 256, 0, stream>>>(wq, wk, wv, wt);
  proj_kernel<<<512, 256, 0, stream>>>(x, wt, qws, kT, vT);
  attn_kernel<<<512, 256, 0, stream>>>(qws, kT, vT, out);
}